// Round 1
// baseline (222.189 us; speedup 1.0000x reference)
//
#include <hip/hip_runtime.h>
#include <math.h>

#define BB 8
#define NN 4096
#define CC 128
#define SS 8
#define HH 64
#define HW 4096              // 64*64
#define QB 8                 // queries per block
#define PLANE_B (HW*CC)      // floats per (plane, batch) in transposed layout
#define SQRT_C 11.3137084989847603904f

// ---------------- transpose planes [B,C,H,W] -> [plane,B,HW,C] ----------------
__global__ __launch_bounds__(128) void transpose_planes(
    const float* __restrict__ pxz, const float* __restrict__ pxy,
    const float* __restrict__ pyz, float* __restrict__ dst) {
  int bid = blockIdx.x;
  int c   = threadIdx.x;
  int hw0 = (bid & 255) * 16;
  int b   = (bid >> 8) & 7;
  int p   = bid >> 11;
  const float* src = (p == 0) ? pxz : (p == 1) ? pxy : pyz;
  const float4* s4 = (const float4*)(src + (size_t)(b * CC + c) * HW + hw0);
  float4 v0 = s4[0], v1 = s4[1], v2 = s4[2], v3 = s4[3];
  float vals[16];
  vals[0]=v0.x; vals[1]=v0.y; vals[2]=v0.z; vals[3]=v0.w;
  vals[4]=v1.x; vals[5]=v1.y; vals[6]=v1.z; vals[7]=v1.w;
  vals[8]=v2.x; vals[9]=v2.y; vals[10]=v2.z; vals[11]=v2.w;
  vals[12]=v3.x; vals[13]=v3.y; vals[14]=v3.z; vals[15]=v3.w;
  float* d = dst + (size_t)(p * BB + b) * PLANE_B + (size_t)hw0 * CC + c;
#pragma unroll
  for (int i = 0; i < 16; ++i) d[i * CC] = vals[i];
}

// ---------------- precompute fused matrices ----------------
// Mt[c'][c] = sqrt(C) * sum_d Wk[c,d]*Wq[c',d]      (so qk_c = u_c + sum_c' Mt[c'][c]*feat_c')
// u[c]     = sqrt(C) * sum_d Wk[c,d]*bq[d]
// W2[c][d] = sum_e Wv[c,e]*Wout[e,d]
// b2[d]    = sum_e bv[e]*Wout[e,d] + bout[d]
__global__ __launch_bounds__(128) void prep_mats(
    const float* __restrict__ Wq, const float* __restrict__ bq,
    const float* __restrict__ Wk,
    const float* __restrict__ Wv, const float* __restrict__ bv,
    const float* __restrict__ Wout, const float* __restrict__ bout,
    float* __restrict__ Mt, float* __restrict__ u,
    float* __restrict__ W2, float* __restrict__ b2) {
  int t = threadIdx.x;
  int blk = blockIdx.x;
  if (blk < 128) {                 // Mt row c' = blk, thread = c
    __shared__ float lwq[128];
    lwq[t] = Wq[blk * 128 + t];
    __syncthreads();
    float acc = 0.f;
#pragma unroll 8
    for (int d = 0; d < 128; ++d) acc += Wk[t * 128 + d] * lwq[d];
    Mt[blk * 128 + t] = SQRT_C * acc;
  } else if (blk < 256) {          // W2 row c = blk-128, thread = d
    int c = blk - 128;
    float acc = 0.f;
#pragma unroll 8
    for (int e = 0; e < 128; ++e) acc += Wv[c * 128 + e] * Wout[e * 128 + t];
    W2[c * 128 + t] = acc;
  } else {                         // u and b2
    float au = 0.f, ab = 0.f;
    for (int d = 0; d < 128; ++d) au += Wk[t * 128 + d] * bq[d];
    u[t] = SQRT_C * au;
    for (int e = 0; e < 128; ++e) ab += bv[e] * Wout[e * 128 + t];
    b2[t] = ab + bout[t];
  }
}

// ---------------- bilinear (border padding, align_corners=True) ----------------
__device__ __forceinline__ float bil(const float* __restrict__ base,
                                     float cx, float cy, int es, int rs) {
  float fx = fminf(fmaxf((cx + 1.f) * 31.5f, 0.f), 63.f);
  float fy = fminf(fmaxf((cy + 1.f) * 31.5f, 0.f), 63.f);
  float x0f = floorf(fx), y0f = floorf(fy);
  int x0 = (int)x0f, y0 = (int)y0f;
  int x1 = min(x0 + 1, 63), y1 = min(y0 + 1, 63);
  float wx = fx - x0f, wy = fy - y0f;
  const float* r0 = base + y0 * rs;
  const float* r1 = base + y1 * rs;
  float f00 = r0[x0 * es], f01 = r0[x1 * es];
  float f10 = r1[x0 * es], f11 = r1[x1 * es];
  float top = f00 + (f01 - f00) * wx;
  float bot = f10 + (f11 - f10) * wx;
  return top + (bot - top) * wy;
}

// ---------------- main fused kernel: one block = 8 queries, thread = channel ----
template <bool TP>
__global__ __launch_bounds__(128) void deform_attn_kernel(
    const float* __restrict__ qpos,
    const float* __restrict__ pxz, const float* __restrict__ pxy,
    const float* __restrict__ pyz, const float* __restrict__ pT,
    const float* __restrict__ Mt, const float* __restrict__ u,
    const float* __restrict__ W2, const float* __restrict__ b2,
    const float* __restrict__ Woff, const float* __restrict__ boff,
    float* __restrict__ out) {
  const int tid = threadIdx.x;
  const int c = tid;
  const int bid = blockIdx.x;
  const int b = bid & 7;              // XCD-locality: batch b -> one XCD (heuristic)
  const int n0 = (bid >> 3) * QB;

  constexpr int es = TP ? CC : 1;
  constexpr int rs = TP ? CC * HH : HH;

  const float *bxz, *bxy, *byz;
  if (TP) {
    bxz = pT + (size_t)(0 * BB + b) * PLANE_B + c;
    bxy = pT + (size_t)(1 * BB + b) * PLANE_B + c;
    byz = pT + (size_t)(2 * BB + b) * PLANE_B + c;
  } else {
    bxz = pxz + (size_t)(b * CC + c) * HW;
    bxy = pxy + (size_t)(b * CC + c) * HW;
    byz = pyz + (size_t)(b * CC + c) * HW;
  }

  __shared__ __align__(16) float sfeat[CC * QB];   // [c'][q]
  __shared__ __align__(16) float sw[CC * QB];      // [c'][q]
  __shared__ float spos[QB * 3];
  __shared__ float soff[QB][SS * 3];
  __shared__ float sred[QB][2][SS];

  if (tid < QB * 3) spos[tid] = qpos[(size_t)(b * NN + n0) * 3 + tid];
  __syncthreads();

  // Phase A: feature sample for QB queries (channel c)
#pragma unroll
  for (int q = 0; q < QB; ++q) {
    float px = spos[q * 3 + 0], py = spos[q * 3 + 1], pz = spos[q * 3 + 2];
    float f = bil(bxz, px, pz, es, rs) + bil(bxy, px, py, es, rs) +
              bil(byz, py, pz, es, rs);
    sfeat[c * QB + q] = f;
  }
  __syncthreads();

  // Phase B: qk_c for all QB queries (matvec with fused M)
  float qk[QB];
  {
    float uc = u[c];
#pragma unroll
    for (int q = 0; q < QB; ++q) qk[q] = uc;
#pragma unroll 4
    for (int cp = 0; cp < CC; ++cp) {
      float m = Mt[cp * CC + c];
      float4 f0 = *(const float4*)&sfeat[cp * QB];
      float4 f1 = *(const float4*)&sfeat[cp * QB + 4];
      qk[0] += m * f0.x; qk[1] += m * f0.y; qk[2] += m * f0.z; qk[3] += m * f0.w;
      qk[4] += m * f1.x; qk[5] += m * f1.y; qk[6] += m * f1.z; qk[7] += m * f1.w;
    }
  }

  // Phase B2: deformable offsets (24 per query, 192 dot products of length 128)
  if (tid < 120) {
    int q = tid / 24, j = tid % 24;
    float acc = boff[j];
    for (int cp = 0; cp < CC; ++cp) acc += sfeat[cp * QB + q] * Woff[cp * 24 + j];
    soff[q][j] = acc;
  }
  if (tid < 72) {
    int q = 5 + tid / 24, j = tid % 24;
    float acc = boff[j];
    for (int cp = 0; cp < CC; ++cp) acc += sfeat[cp * QB + q] * Woff[cp * 24 + j];
    soff[q][j] = acc;
  }
  __syncthreads();

  // Phase C: aux sampling + logits + softmax + weighted aux
  const int wvid = tid >> 6;
  for (int q = 0; q < QB; ++q) {
    float px = spos[q * 3 + 0], py = spos[q * 3 + 1], pz = spos[q * 3 + 2];
    float a8[SS];
#pragma unroll
    for (int j = 0; j < SS; ++j) {
      float ox = px + soff[q][j * 3 + 0];
      float oy = py + soff[q][j * 3 + 1];
      float oz = pz + soff[q][j * 3 + 2];
      float a = bil(bxz, ox, oz, es, rs) + bil(bxy, ox, oy, es, rs) +
                bil(byz, oy, oz, es, rs);
      a8[j] = a;
      float p = a * qk[q];
#pragma unroll
      for (int m = 1; m < 64; m <<= 1) p += __shfl_xor(p, m);
      if ((tid & 63) == 0) sred[q][wvid][j] = p;
    }
    __syncthreads();
    float attn[SS];
    float mx = -INFINITY;
#pragma unroll
    for (int j = 0; j < SS; ++j) {
      attn[j] = sred[q][0][j] + sred[q][1][j];
      mx = fmaxf(mx, attn[j]);
    }
    float den = 0.f;
#pragma unroll
    for (int j = 0; j < SS; ++j) { attn[j] = expf(attn[j] - mx); den += attn[j]; }
    float inv = 1.f / den;
    float w = 0.f;
#pragma unroll
    for (int j = 0; j < SS; ++j) w += attn[j] * a8[j];
    sw[c * QB + q] = w * inv;
  }
  __syncthreads();

  // Phase F: out = w @ (Wv@Wout) + (bv@Wout + bout) + feature
  float o[QB];
  {
    float bb = b2[c];
#pragma unroll
    for (int q = 0; q < QB; ++q) o[q] = bb;
#pragma unroll 4
    for (int cp = 0; cp < CC; ++cp) {
      float wv2 = W2[cp * CC + c];
      float4 w0 = *(const float4*)&sw[cp * QB];
      float4 w1 = *(const float4*)&sw[cp * QB + 4];
      o[0] += wv2 * w0.x; o[1] += wv2 * w0.y; o[2] += wv2 * w0.z; o[3] += wv2 * w0.w;
      o[4] += wv2 * w1.x; o[5] += wv2 * w1.y; o[6] += wv2 * w1.z; o[7] += wv2 * w1.w;
    }
  }
#pragma unroll
  for (int q = 0; q < QB; ++q) {
    out[(size_t)(b * NN + n0 + q) * CC + c] = o[q] + sfeat[c * QB + q];
  }
}

extern "C" void kernel_launch(void* const* d_in, const int* in_sizes, int n_in,
                              void* d_out, int out_size, void* d_ws, size_t ws_size,
                              hipStream_t stream) {
  const float* qpos = (const float*)d_in[0];
  const float* pxz  = (const float*)d_in[1];
  const float* pxy  = (const float*)d_in[2];
  const float* pyz  = (const float*)d_in[3];
  const float* Wq   = (const float*)d_in[4];
  const float* bq   = (const float*)d_in[5];
  const float* Wk   = (const float*)d_in[6];
  // d_in[7] = bk: unused — q·bk is constant over the S axis and cancels in softmax
  const float* Wv   = (const float*)d_in[8];
  const float* bv   = (const float*)d_in[9];
  const float* Wout = (const float*)d_in[10];
  const float* bout = (const float*)d_in[11];
  const float* Woff = (const float*)d_in[12];
  const float* boff = (const float*)d_in[13];
  float* out = (float*)d_out;

  float* w = (float*)d_ws;
  const size_t nT = (size_t)3 * BB * HW * CC;            // 12.58M floats
  const size_t matFloats = 16384 + 128 + 16384 + 128;    // Mt,u,W2,b2
  bool tp = ws_size >= (nT + matFloats) * sizeof(float);

  float* wsT  = w;
  float* wsMt = tp ? (w + nT) : w;
  float* wsU  = wsMt + 16384;
  float* wsW2 = wsU + 128;
  float* wsB2 = wsW2 + 16384;

  if (tp) transpose_planes<<<3 * BB * (HW / 16), 128, 0, stream>>>(pxz, pxy, pyz, wsT);
  prep_mats<<<257, 128, 0, stream>>>(Wq, bq, Wk, Wv, bv, Wout, bout,
                                     wsMt, wsU, wsW2, wsB2);
  if (tp)
    deform_attn_kernel<true><<<(BB * NN) / QB, 128, 0, stream>>>(
        qpos, pxz, pxy, pyz, wsT, wsMt, wsU, wsW2, wsB2, Woff, boff, out);
  else
    deform_attn_kernel<false><<<(BB * NN) / QB, 128, 0, stream>>>(
        qpos, pxz, pxy, pyz, nullptr, wsMt, wsU, wsW2, wsB2, Woff, boff, out);
}